// Round 1
// baseline (2179.660 us; speedup 1.0000x reference)
//
#include <hip/hip_runtime.h>
#include <hip/hip_bf16.h>
#include <cstdint>

// Problem constants (fixed): B=4, S=2048, E=1024, H=16, HD=64
#define NB 4
#define NS 2048
#define NE 1024
#define NH 16

typedef __attribute__((ext_vector_type(8))) short bf16x8;   // 8 bf16 (4 VGPRs)
typedef __attribute__((ext_vector_type(4))) float f32x4;    // MFMA C/D

__device__ __forceinline__ unsigned short f2bf(float f) {
  unsigned u = __float_as_uint(f);
  u += 0x7fffu + ((u >> 16) & 1u);   // RNE
  return (unsigned short)(u >> 16);
}
__device__ __forceinline__ float bf2f_lo(unsigned u) { return __uint_as_float(u << 16); }
__device__ __forceinline__ float bf2f_hi(unsigned u) { return __uint_as_float(u & 0xffff0000u); }

// ---------------- cast fp32 -> bf16 ----------------
__global__ __launch_bounds__(256) void cast_k(const float* __restrict__ in,
                                              unsigned short* __restrict__ out, int n4) {
  int idx = blockIdx.x * 256 + threadIdx.x;
  if (idx >= n4) return;
  float4 v = ((const float4*)in)[idx];
  ushort4 o;
  o.x = f2bf(v.x); o.y = f2bf(v.y); o.z = f2bf(v.z); o.w = f2bf(v.w);
  ((ushort4*)out)[idx] = o;
}

// ---------------- C[M,N] = A[M,K] @ B[N,K]^T + bias ----------------
// 128x128 tile, 4 waves in 2x2, each wave 4x4 of 16x16x32 MFMA. BK=32.
// LDS rows padded to 40 elems (80B) -> frag ds_read_b128 is <=2-way (free).
template <int STORE_BF16>
__global__ __launch_bounds__(256, 2) void gemm_bt(
    const unsigned short* __restrict__ A,   // [M,K] bf16
    const unsigned short* __restrict__ Bm,  // [N,K] bf16
    const float* __restrict__ bias,         // [N] fp32
    void* __restrict__ Cv, int M, int N, int K) {
  const int LDT = 40;
  __shared__ unsigned short As[128 * 40];
  __shared__ unsigned short Bs[128 * 40];
  const int tid = threadIdx.x;
  const int lane = tid & 63, wave = tid >> 6;
  const int m0 = blockIdx.y * 128, n0 = blockIdx.x * 128;
  const int wm = (wave >> 1) * 64, wn = (wave & 1) * 64;
  const int fr = lane & 15, fq = lane >> 4;

  f32x4 acc[4][4];
#pragma unroll
  for (int i = 0; i < 4; i++)
#pragma unroll
    for (int j = 0; j < 4; j++) acc[i][j] = (f32x4){0.f, 0.f, 0.f, 0.f};

  const int r0 = tid >> 2, r1 = r0 + 64;
  const int c0 = (tid & 3) * 8;

  for (int kt = 0; kt < K; kt += 32) {
    uint4 a0 = *(const uint4*)(A + (size_t)(m0 + r0) * K + kt + c0);
    uint4 a1 = *(const uint4*)(A + (size_t)(m0 + r1) * K + kt + c0);
    uint4 b0 = *(const uint4*)(Bm + (size_t)(n0 + r0) * K + kt + c0);
    uint4 b1 = *(const uint4*)(Bm + (size_t)(n0 + r1) * K + kt + c0);
    __syncthreads();
    *(uint4*)(As + r0 * LDT + c0) = a0;
    *(uint4*)(As + r1 * LDT + c0) = a1;
    *(uint4*)(Bs + r0 * LDT + c0) = b0;
    *(uint4*)(Bs + r1 * LDT + c0) = b1;
    __syncthreads();
    bf16x8 af[4], bf[4];
#pragma unroll
    for (int i = 0; i < 4; i++)
      af[i] = *(const bf16x8*)(As + (wm + i * 16 + fr) * LDT + fq * 8);
#pragma unroll
    for (int j = 0; j < 4; j++)
      bf[j] = *(const bf16x8*)(Bs + (wn + j * 16 + fr) * LDT + fq * 8);
#pragma unroll
    for (int i = 0; i < 4; i++)
#pragma unroll
      for (int j = 0; j < 4; j++)
        acc[i][j] = __builtin_amdgcn_mfma_f32_16x16x32_bf16(af[i], bf[j], acc[i][j], 0, 0, 0);
  }

#pragma unroll
  for (int i = 0; i < 4; i++) {
#pragma unroll
    for (int j = 0; j < 4; j++) {
      int col = n0 + wn + j * 16 + fr;
      float bval = bias[col];
#pragma unroll
      for (int r = 0; r < 4; r++) {
        int row = m0 + wm + i * 16 + fq * 4 + r;
        float v = acc[i][j][r] + bval;
        if (STORE_BF16)
          ((unsigned short*)Cv)[(size_t)row * N + col] = f2bf(v);
        else
          ((float*)Cv)[(size_t)row * N + col] = v;
      }
    }
  }
}

// ---------------- causal flash attention (vector ALU) ----------------
// qkv: [B*S, 3072] bf16, per-head layout col = h*192 + {0:q,64:k,128:v} + d
// out: [B*S, 1024] bf16, col = h*64 + d
// 1 thread = 1 query row; K/V staged 64 keys at a time into LDS (fp32).
__global__ __launch_bounds__(256, 2) void attn_k(
    const unsigned short* __restrict__ qkv, unsigned short* __restrict__ outa) {
  __shared__ float Ks[64 * 64];
  __shared__ float Vs[64 * 64];
  const int tid = threadIdx.x;
  const int qb = 7 - (int)blockIdx.x;  // heavy q-blocks dispatched first
  const int bh = blockIdx.y;
  const int b = bh >> 4, h = bh & 15;
  const int i = qb * 256 + tid;
  const size_t rowbase = ((size_t)(b * NS + i)) * 3072 + h * 192;

  float q[64], acc[64];
#pragma unroll
  for (int c = 0; c < 8; c++) {
    uint4 u = ((const uint4*)(qkv + rowbase))[c];
    q[c * 8 + 0] = bf2f_lo(u.x); q[c * 8 + 1] = bf2f_hi(u.x);
    q[c * 8 + 2] = bf2f_lo(u.y); q[c * 8 + 3] = bf2f_hi(u.y);
    q[c * 8 + 4] = bf2f_lo(u.z); q[c * 8 + 5] = bf2f_hi(u.z);
    q[c * 8 + 6] = bf2f_lo(u.w); q[c * 8 + 7] = bf2f_hi(u.w);
  }
#pragma unroll
  for (int d = 0; d < 64; d++) acc[d] = 0.f;
  float m = -INFINITY, l = 0.f;

  const int ktiles = qb * 4 + 4;
  for (int kt = 0; kt < ktiles; kt++) {
    const int k0 = kt * 64;
    __syncthreads();
#pragma unroll
    for (int it = 0; it < 2; it++) {
      int c = tid + it * 256;
      int r = c >> 3, cc = (c & 7) * 8;
      size_t src = ((size_t)(b * NS + k0 + r)) * 3072 + h * 192 + cc;
      uint4 kv = *(const uint4*)(qkv + src + 64);
      uint4 vv = *(const uint4*)(qkv + src + 128);
      float4 f0, f1;
      f0.x = bf2f_lo(kv.x); f0.y = bf2f_hi(kv.x); f0.z = bf2f_lo(kv.y); f0.w = bf2f_hi(kv.y);
      f1.x = bf2f_lo(kv.z); f1.y = bf2f_hi(kv.z); f1.z = bf2f_lo(kv.w); f1.w = bf2f_hi(kv.w);
      *(float4*)(Ks + r * 64 + cc) = f0;
      *(float4*)(Ks + r * 64 + cc + 4) = f1;
      f0.x = bf2f_lo(vv.x); f0.y = bf2f_hi(vv.x); f0.z = bf2f_lo(vv.y); f0.w = bf2f_hi(vv.y);
      f1.x = bf2f_lo(vv.z); f1.y = bf2f_hi(vv.z); f1.z = bf2f_lo(vv.w); f1.w = bf2f_hi(vv.w);
      *(float4*)(Vs + r * 64 + cc) = f0;
      *(float4*)(Vs + r * 64 + cc + 4) = f1;
    }
    __syncthreads();
    const bool full = (kt < qb * 4);  // uniform per block
    const float4* K4 = (const float4*)Ks;
    const float4* V4 = (const float4*)Vs;
#pragma unroll 1
    for (int c8 = 0; c8 < 8; c8++) {
      float sv[8];
#pragma unroll
      for (int jj = 0; jj < 8; jj++) {
        int j = c8 * 8 + jj;
        float s = 0.f;
#pragma unroll
        for (int d4 = 0; d4 < 16; d4++) {
          float4 kv = K4[j * 16 + d4];  // wave-broadcast LDS read
          s += q[d4 * 4 + 0] * kv.x + q[d4 * 4 + 1] * kv.y +
               q[d4 * 4 + 2] * kv.z + q[d4 * 4 + 3] * kv.w;
        }
        s *= 0.125f;  // 1/sqrt(64)
        if (!full && (k0 + j > i)) s = -INFINITY;
        sv[jj] = s;
      }
      float cm = sv[0];
#pragma unroll
      for (int jj = 1; jj < 8; jj++) cm = fmaxf(cm, sv[jj]);
      float mn = fmaxf(m, cm);          // finite after first chunk (key 0 always valid)
      float alpha = __expf(m - mn);     // exp(-inf)=0 on first chunk; exp(0)=1 if no new max
      float p[8], ps = 0.f;
#pragma unroll
      for (int jj = 0; jj < 8; jj++) { p[jj] = __expf(sv[jj] - mn); ps += p[jj]; }
      l = l * alpha + ps;
      m = mn;
#pragma unroll
      for (int d4 = 0; d4 < 16; d4++) {
        float tx = 0.f, ty = 0.f, tz = 0.f, tw = 0.f;
#pragma unroll
        for (int jj = 0; jj < 8; jj++) {
          float4 vv = V4[(c8 * 8 + jj) * 16 + d4];
          tx += p[jj] * vv.x; ty += p[jj] * vv.y; tz += p[jj] * vv.z; tw += p[jj] * vv.w;
        }
        acc[d4 * 4 + 0] = acc[d4 * 4 + 0] * alpha + tx;
        acc[d4 * 4 + 1] = acc[d4 * 4 + 1] * alpha + ty;
        acc[d4 * 4 + 2] = acc[d4 * 4 + 2] * alpha + tz;
        acc[d4 * 4 + 3] = acc[d4 * 4 + 3] * alpha + tw;
      }
    }
  }
  float inv = 1.f / l;
  size_t obase = ((size_t)(b * NS + i)) * 1024 + h * 64;
  unsigned* op = (unsigned*)outa;
#pragma unroll
  for (int c = 0; c < 32; c++) {
    unsigned lo = f2bf(acc[2 * c] * inv);
    unsigned hi = f2bf(acc[2 * c + 1] * inv);
    op[obase / 2 + c] = lo | (hi << 16);
  }
}

// ---------------- launch ----------------
// ws layout (bf16 elems): xb[8192*1024] | wqkv[3072*1024] | wo[1024*1024]
//                         | qkv[8192*3072] | att[8192*1024]  -> ~88 MB total
extern "C" void kernel_launch(void* const* d_in, const int* in_sizes, int n_in,
                              void* d_out, int out_size, void* d_ws, size_t ws_size,
                              hipStream_t stream) {
  const float* x     = (const float*)d_in[0];
  const float* qkv_w = (const float*)d_in[1];
  const float* qkv_b = (const float*)d_in[2];
  const float* out_w = (const float*)d_in[3];
  const float* out_b = (const float*)d_in[4];

  unsigned short* xb   = (unsigned short*)d_ws;
  unsigned short* wqkv = xb + (size_t)8192 * 1024;
  unsigned short* wo   = wqkv + (size_t)3072 * 1024;
  unsigned short* qkv  = wo + (size_t)1024 * 1024;
  unsigned short* att  = qkv + (size_t)8192 * 3072;

  cast_k<<<(2097152 + 255) / 256, 256, 0, stream>>>(x, xb, 2097152);       // 8.39M elems /4
  cast_k<<<(786432 + 255) / 256, 256, 0, stream>>>(qkv_w, wqkv, 786432);   // 3.15M /4
  cast_k<<<(262144 + 255) / 256, 256, 0, stream>>>(out_w, wo, 262144);     // 1.05M /4

  gemm_bt<1><<<dim3(24, 64), 256, 0, stream>>>(xb, wqkv, qkv_b, (void*)qkv,
                                               8192, 3072, 1024);
  attn_k<<<dim3(8, 64), 256, 0, stream>>>(qkv, att);
  gemm_bt<0><<<dim3(8, 64), 256, 0, stream>>>(att, wo, out_b, d_out,
                                              8192, 1024, 1024);
}

// Round 2
// 407.398 us; speedup vs baseline: 5.3502x; 5.3502x over previous
//
#include <hip/hip_runtime.h>
#include <hip/hip_bf16.h>
#include <cstdint>

// Problem constants (fixed): B=4, S=2048, E=1024, H=16, HD=64
#define NB 4
#define NS 2048
#define NE 1024
#define NH 16

typedef __attribute__((ext_vector_type(8))) short bf16x8;   // 8 bf16 (4 VGPRs)
typedef __attribute__((ext_vector_type(4))) float f32x4;    // MFMA C/D

__device__ __forceinline__ unsigned short f2bf(float f) {
  unsigned u = __float_as_uint(f);
  u += 0x7fffu + ((u >> 16) & 1u);   // RNE
  return (unsigned short)(u >> 16);
}

// ---------------- cast fp32 -> bf16 ----------------
__global__ __launch_bounds__(256) void cast_k(const float* __restrict__ in,
                                              unsigned short* __restrict__ out, int n4) {
  int idx = blockIdx.x * 256 + threadIdx.x;
  if (idx >= n4) return;
  float4 v = ((const float4*)in)[idx];
  ushort4 o;
  o.x = f2bf(v.x); o.y = f2bf(v.y); o.z = f2bf(v.z); o.w = f2bf(v.w);
  ((ushort4*)out)[idx] = o;
}

// ---------------- C[M,N] = A[M,K] @ B[N,K]^T + bias ----------------
// 128x128 tile, 4 waves in 2x2, each wave 4x4 of 16x16x32 MFMA. BK=32.
template <int STORE_BF16>
__global__ __launch_bounds__(256, 2) void gemm_bt(
    const unsigned short* __restrict__ A,   // [M,K] bf16
    const unsigned short* __restrict__ Bm,  // [N,K] bf16
    const float* __restrict__ bias,         // [N] fp32
    void* __restrict__ Cv, int M, int N, int K) {
  const int LDT = 40;
  __shared__ unsigned short As[128 * 40];
  __shared__ unsigned short Bs[128 * 40];
  const int tid = threadIdx.x;
  const int lane = tid & 63, wave = tid >> 6;
  const int m0 = blockIdx.y * 128, n0 = blockIdx.x * 128;
  const int wm = (wave >> 1) * 64, wn = (wave & 1) * 64;
  const int fr = lane & 15, fq = lane >> 4;

  f32x4 acc[4][4];
#pragma unroll
  for (int i = 0; i < 4; i++)
#pragma unroll
    for (int j = 0; j < 4; j++) acc[i][j] = (f32x4){0.f, 0.f, 0.f, 0.f};

  const int r0 = tid >> 2, r1 = r0 + 64;
  const int c0 = (tid & 3) * 8;

  for (int kt = 0; kt < K; kt += 32) {
    uint4 a0 = *(const uint4*)(A + (size_t)(m0 + r0) * K + kt + c0);
    uint4 a1 = *(const uint4*)(A + (size_t)(m0 + r1) * K + kt + c0);
    uint4 b0 = *(const uint4*)(Bm + (size_t)(n0 + r0) * K + kt + c0);
    uint4 b1 = *(const uint4*)(Bm + (size_t)(n0 + r1) * K + kt + c0);
    __syncthreads();
    *(uint4*)(As + r0 * LDT + c0) = a0;
    *(uint4*)(As + r1 * LDT + c0) = a1;
    *(uint4*)(Bs + r0 * LDT + c0) = b0;
    *(uint4*)(Bs + r1 * LDT + c0) = b1;
    __syncthreads();
    bf16x8 af[4], bf[4];
#pragma unroll
    for (int i = 0; i < 4; i++)
      af[i] = *(const bf16x8*)(As + (wm + i * 16 + fr) * LDT + fq * 8);
#pragma unroll
    for (int j = 0; j < 4; j++)
      bf[j] = *(const bf16x8*)(Bs + (wn + j * 16 + fr) * LDT + fq * 8);
#pragma unroll
    for (int i = 0; i < 4; i++)
#pragma unroll
      for (int j = 0; j < 4; j++)
        acc[i][j] = __builtin_amdgcn_mfma_f32_16x16x32_bf16(af[i], bf[j], acc[i][j], 0, 0, 0);
  }

#pragma unroll
  for (int i = 0; i < 4; i++) {
#pragma unroll
    for (int j = 0; j < 4; j++) {
      int col = n0 + wn + j * 16 + fr;
      float bval = bias[col];
#pragma unroll
      for (int r = 0; r < 4; r++) {
        int row = m0 + wm + i * 16 + fq * 4 + r;
        float v = acc[i][j][r] + bval;
        if (STORE_BF16)
          ((unsigned short*)Cv)[(size_t)row * N + col] = f2bf(v);
        else
          ((float*)Cv)[(size_t)row * N + col] = v;
      }
    }
  }
}

// ---------------- MFMA causal flash attention ----------------
// qkv: [B*S, 3072] bf16, head h cols: q=h*192+[0,64), k=+64, v=+128
// out: [B*S, 1024] bf16, col = h*64 + d
// Block = 4 waves; wave w owns 16 q-rows (q0 = qt*64 + w*16).
// Key loop: 64-key tiles. K row-major LDS; V transposed LDS; P via LDS
// round-trip (C-layout -> A-layout).
#define LDK 72   // elems; row = 144B = 9*16 -> 16B-aligned rows, 2-way banks
__global__ __launch_bounds__(256, 2) void attn_k(
    const unsigned short* __restrict__ qkv, unsigned short* __restrict__ outa) {
  __shared__ __align__(16) unsigned short Ks[64 * LDK];
  __shared__ __align__(16) unsigned short VTs[64 * LDK];
  __shared__ __align__(16) unsigned short Ps[4 * 16 * LDK];
  const int tid = threadIdx.x;
  const int lane = tid & 63, wave = tid >> 6;
  const int fc = lane & 15, fq = lane >> 4;
  const int qt = 31 - (int)blockIdx.x;      // heavy q-tiles dispatch first
  const int bh = blockIdx.y;
  const int b = bh >> 4, h = bh & 15;
  const int q0 = qt * 64 + wave * 16;       // this wave's first q row

  // Q A-frags (held for whole kernel): A[m=fc][k=fq*8+j (+32)]
  const unsigned short* qrow = qkv + ((size_t)(b * NS + q0 + fc)) * 3072 + h * 192;
  bf16x8 qa0 = *(const bf16x8*)(qrow + fq * 8);
  bf16x8 qa1 = *(const bf16x8*)(qrow + 32 + fq * 8);

  f32x4 O[4];
#pragma unroll
  for (int dt = 0; dt < 4; dt++) O[dt] = (f32x4){0.f, 0.f, 0.f, 0.f};
  float mrow[4], lrow[4];
#pragma unroll
  for (int r = 0; r < 4; r++) { mrow[r] = -3e38f; lrow[r] = 0.f; }

  // staging assignments
  const int kr = tid >> 3, kc = (tid & 7) * 8;        // K: 8 lanes/row, 128B coalesced
  const int vk = (tid & 31) * 2, vd = (tid >> 5) * 8; // V: row-pair -> b32 transposed writes

  for (int kb = 0; kb <= qt; kb++) {
    const int k0 = kb * 64;
    __syncthreads();
    // ---- stage K rows [64 x 64] row-major
#pragma unroll
    for (int it = 0; it < 2; it++) {
      int r = kr + it * 32;
      const unsigned short* src =
          qkv + ((size_t)(b * NS + k0 + r)) * 3072 + h * 192 + 64 + kc;
      *(uint4*)(Ks + r * LDK + kc) = *(const uint4*)src;
    }
    // ---- stage V transposed: VTs[d][k] = V[k][d]
    {
      const unsigned short* s0 =
          qkv + ((size_t)(b * NS + k0 + vk)) * 3072 + h * 192 + 128 + vd;
      uint4 v0 = *(const uint4*)s0;
      uint4 v1 = *(const uint4*)(s0 + 3072);
      unsigned a0[4] = {v0.x, v0.y, v0.z, v0.w};
      unsigned a1[4] = {v1.x, v1.y, v1.z, v1.w};
#pragma unroll
      for (int jj = 0; jj < 4; jj++) {
        unsigned lo = (a0[jj] & 0xffffu) | (a1[jj] << 16);                  // d = vd+2jj
        unsigned hi = (a0[jj] >> 16) | (a1[jj] & 0xffff0000u);              // d = vd+2jj+1
        *(unsigned*)(VTs + (size_t)(vd + 2 * jj) * LDK + vk) = lo;
        *(unsigned*)(VTs + (size_t)(vd + 2 * jj + 1) * LDK + vk) = hi;
      }
    }
    __syncthreads();

    // ---- QK^T: S[t] = Q(16 rows) x K(keys t*16..t*16+15)^T
    f32x4 S[4];
#pragma unroll
    for (int t = 0; t < 4; t++) {
      bf16x8 kb0 = *(const bf16x8*)(Ks + (t * 16 + fc) * LDK + fq * 8);
      bf16x8 kb1 = *(const bf16x8*)(Ks + (t * 16 + fc) * LDK + 32 + fq * 8);
      f32x4 s = (f32x4){0.f, 0.f, 0.f, 0.f};
      s = __builtin_amdgcn_mfma_f32_16x16x32_bf16(qa0, kb0, s, 0, 0, 0);
      s = __builtin_amdgcn_mfma_f32_16x16x32_bf16(qa1, kb1, s, 0, 0, 0);
      S[t] = s;
    }
    // scale + causal mask (C layout: row=fq*4+r, col=t*16+fc)
#pragma unroll
    for (int t = 0; t < 4; t++)
#pragma unroll
      for (int r = 0; r < 4; r++) S[t][r] *= 0.125f;
    if (kb == qt) {  // diagonal tile (wave-uniform branch)
#pragma unroll
      for (int t = 0; t < 4; t++)
#pragma unroll
        for (int r = 0; r < 4; r++)
          if (k0 + t * 16 + fc > q0 + fq * 4 + r) S[t][r] = -3e38f;
    }
    // ---- online softmax (per-lane 4 rows, reduce across 16-lane quad)
    float cm[4], alpha[4], ps[4];
#pragma unroll
    for (int r = 0; r < 4; r++)
      cm[r] = fmaxf(fmaxf(S[0][r], S[1][r]), fmaxf(S[2][r], S[3][r]));
#pragma unroll
    for (int d = 1; d < 16; d <<= 1)
#pragma unroll
      for (int r = 0; r < 4; r++) cm[r] = fmaxf(cm[r], __shfl_xor(cm[r], d, 64));
#pragma unroll
    for (int r = 0; r < 4; r++) {
      float mn = fmaxf(mrow[r], cm[r]);
      alpha[r] = __expf(mrow[r] - mn);
      mrow[r] = mn;
      ps[r] = 0.f;
    }
#pragma unroll
    for (int t = 0; t < 4; t++)
#pragma unroll
      for (int r = 0; r < 4; r++) {
        float p = __expf(S[t][r] - mrow[r]);
        S[t][r] = p;
        ps[r] += p;
      }
#pragma unroll
    for (int d = 1; d < 16; d <<= 1)
#pragma unroll
      for (int r = 0; r < 4; r++) ps[r] += __shfl_xor(ps[r], d, 64);
#pragma unroll
    for (int r = 0; r < 4; r++) lrow[r] = lrow[r] * alpha[r] + ps[r];

    // ---- P: C layout -> LDS -> A layout (per-wave private buffer)
    unsigned short* Pw = Ps + wave * 16 * LDK;
#pragma unroll
    for (int t = 0; t < 4; t++)
#pragma unroll
      for (int r = 0; r < 4; r++)
        Pw[(fq * 4 + r) * LDK + t * 16 + fc] = f2bf(S[t][r]);
    bf16x8 pa0 = *(const bf16x8*)(Pw + fc * LDK + fq * 8);
    bf16x8 pa1 = *(const bf16x8*)(Pw + fc * LDK + 32 + fq * 8);

    // ---- rescale O, then PV
#pragma unroll
    for (int dt = 0; dt < 4; dt++)
#pragma unroll
      for (int r = 0; r < 4; r++) O[dt][r] *= alpha[r];
#pragma unroll
    for (int dt = 0; dt < 4; dt++) {
      bf16x8 vb0 = *(const bf16x8*)(VTs + (dt * 16 + fc) * LDK + fq * 8);
      bf16x8 vb1 = *(const bf16x8*)(VTs + (dt * 16 + fc) * LDK + 32 + fq * 8);
      O[dt] = __builtin_amdgcn_mfma_f32_16x16x32_bf16(pa0, vb0, O[dt], 0, 0, 0);
      O[dt] = __builtin_amdgcn_mfma_f32_16x16x32_bf16(pa1, vb1, O[dt], 0, 0, 0);
    }
  }

  // ---- epilogue: O /= l, store bf16 (row=q0+fq*4+r, col=h*64+dt*16+fc)
  float inv[4];
#pragma unroll
  for (int r = 0; r < 4; r++) inv[r] = 1.f / lrow[r];
#pragma unroll
  for (int dt = 0; dt < 4; dt++)
#pragma unroll
    for (int r = 0; r < 4; r++) {
      size_t row = (size_t)(b * NS) + q0 + fq * 4 + r;
      outa[row * 1024 + h * 64 + dt * 16 + fc] = f2bf(O[dt][r] * inv[r]);
    }
}

// ---------------- launch ----------------
// ws layout (bf16 elems): xb[8192*1024] | wqkv[3072*1024] | wo[1024*1024]
//                         | qkv[8192*3072] | att[8192*1024]
extern "C" void kernel_launch(void* const* d_in, const int* in_sizes, int n_in,
                              void* d_out, int out_size, void* d_ws, size_t ws_size,
                              hipStream_t stream) {
  const float* x     = (const float*)d_in[0];
  const float* qkv_w = (const float*)d_in[1];
  const float* qkv_b = (const float*)d_in[2];
  const float* out_w = (const float*)d_in[3];
  const float* out_b = (const float*)d_in[4];

  unsigned short* xb   = (unsigned short*)d_ws;
  unsigned short* wqkv = xb + (size_t)8192 * 1024;
  unsigned short* wo   = wqkv + (size_t)3072 * 1024;
  unsigned short* qkv  = wo + (size_t)1024 * 1024;
  unsigned short* att  = qkv + (size_t)8192 * 3072;

  cast_k<<<(2097152 + 255) / 256, 256, 0, stream>>>(x, xb, 2097152);
  cast_k<<<(786432 + 255) / 256, 256, 0, stream>>>(qkv_w, wqkv, 786432);
  cast_k<<<(262144 + 255) / 256, 256, 0, stream>>>(out_w, wo, 262144);

  gemm_bt<1><<<dim3(24, 64), 256, 0, stream>>>(xb, wqkv, qkv_b, (void*)qkv,
                                               8192, 3072, 1024);
  attn_k<<<dim3(32, 64), 256, 0, stream>>>(qkv, att);
  gemm_bt<0><<<dim3(8, 64), 256, 0, stream>>>(att, wo, out_b, d_out,
                                              8192, 1024, 1024);
}

// Round 3
// 291.220 us; speedup vs baseline: 7.4846x; 1.3989x over previous
//
#include <hip/hip_runtime.h>
#include <hip/hip_bf16.h>
#include <cstdint>

// Problem constants (fixed): B=4, S=2048, E=1024, H=16, HD=64
#define NB 4
#define NS 2048
#define NE 1024
#define NH 16

typedef __attribute__((ext_vector_type(8))) short bf16x8;   // 8 bf16 (4 VGPRs)
typedef __attribute__((ext_vector_type(4))) float f32x4;    // MFMA C/D

__device__ __forceinline__ unsigned short f2bf(float f) {
  unsigned u = __float_as_uint(f);
  u += 0x7fffu + ((u >> 16) & 1u);   // RNE
  return (unsigned short)(u >> 16);
}

// async global->LDS, 16B/lane. LDS dest = wave-uniform base + lane*16.
__device__ __forceinline__ void gl_lds16(const void* g, void* l) {
  __builtin_amdgcn_global_load_lds(
      (const __attribute__((address_space(1))) void*)g,
      (__attribute__((address_space(3))) void*)l, 16, 0, 0);
}

// ---------------- cast fp32 -> bf16 ----------------
__global__ __launch_bounds__(256) void cast_k(const float* __restrict__ in,
                                              unsigned short* __restrict__ out, int n4) {
  int idx = blockIdx.x * 256 + threadIdx.x;
  if (idx >= n4) return;
  float4 v = ((const float4*)in)[idx];
  ushort4 o;
  o.x = f2bf(v.x); o.y = f2bf(v.y); o.z = f2bf(v.z); o.w = f2bf(v.w);
  ((ushort4*)out)[idx] = o;
}

// ---------------- C[M,N] = A[M,K] @ B[N,K]^T + bias ----------------
// 128x128 tile, 4 waves 2x2, 4x4 MFMA/wave, BK=64, global_load_lds staging.
// LDS unpadded (row=64 elems); 16B-chunk XOR swizzle: LDS[row][c8] holds
// global chunk c8^(row&7)  -> conflict-free ds_read_b128 frag reads.
template <int STORE_BF16>
__global__ __launch_bounds__(256, 2) void gemm_bt(
    const unsigned short* __restrict__ A,   // [M,K] bf16
    const unsigned short* __restrict__ Bm,  // [N,K] bf16
    const float* __restrict__ bias,         // [N] fp32
    void* __restrict__ Cv, int M, int N, int K) {
  __shared__ __align__(16) unsigned short As[128 * 64];
  __shared__ __align__(16) unsigned short Bs[128 * 64];
  const int tid = threadIdx.x;
  const int lane = tid & 63, wave = tid >> 6;
  const int m0 = blockIdx.y * 128, n0 = blockIdx.x * 128;
  const int wm = (wave >> 1) * 64, wn = (wave & 1) * 64;
  const int fr = lane & 15, fq = lane >> 4;

  f32x4 acc[4][4];
#pragma unroll
  for (int i = 0; i < 4; i++)
#pragma unroll
    for (int j = 0; j < 4; j++) acc[i][j] = (f32x4){0.f, 0.f, 0.f, 0.f};

  const int srow = lane >> 3;                   // 0..7 within 8-row chunk
  const int scol = ((lane & 7) ^ srow) * 8;     // swizzled global col (elems)

  for (int kt = 0; kt < K; kt += 64) {
    __syncthreads();
#pragma unroll
    for (int c = 0; c < 4; c++) {
      const int chunk = wave * 4 + c;           // 0..15, 8 rows each
      const int row = chunk * 8 + srow;
      gl_lds16(A + (size_t)(m0 + row) * K + kt + scol, As + chunk * 512);
      gl_lds16(Bm + (size_t)(n0 + row) * K + kt + scol, Bs + chunk * 512);
    }
    __syncthreads();
#pragma unroll
    for (int s = 0; s < 2; s++) {
      bf16x8 af[4], bf[4];
#pragma unroll
      for (int i = 0; i < 4; i++)
        af[i] = *(const bf16x8*)(As + (wm + i * 16 + fr) * 64 +
                                 (((s * 4 + fq) ^ (fr & 7)) * 8));
#pragma unroll
      for (int j = 0; j < 4; j++)
        bf[j] = *(const bf16x8*)(Bs + (wn + j * 16 + fr) * 64 +
                                 (((s * 4 + fq) ^ (fr & 7)) * 8));
#pragma unroll
      for (int i = 0; i < 4; i++)
#pragma unroll
        for (int j = 0; j < 4; j++)
          acc[i][j] = __builtin_amdgcn_mfma_f32_16x16x32_bf16(af[i], bf[j], acc[i][j], 0, 0, 0);
    }
  }

#pragma unroll
  for (int i = 0; i < 4; i++) {
#pragma unroll
    for (int j = 0; j < 4; j++) {
      int col = n0 + wn + j * 16 + fr;
      float bval = bias[col];
#pragma unroll
      for (int r = 0; r < 4; r++) {
        int row = m0 + wm + i * 16 + fq * 4 + r;
        float v = acc[i][j][r] + bval;
        if (STORE_BF16)
          ((unsigned short*)Cv)[(size_t)row * N + col] = f2bf(v);
        else
          ((float*)Cv)[(size_t)row * N + col] = v;
      }
    }
  }
}

// ---------------- MFMA causal flash attention, S^T orientation ----------------
// qkv: [B*S, 3072] bf16, head h: q=h*192+[0,64), k=+64, v=+128
// S^T = K x Q^T  (A=K -> m=key, B=Q -> n=q): per-q softmax stats are
// column-wise: 16 keys in-lane + 2 shuffles (xor16,32). O^T = V^T x P
// comes out with d=row, q=col; alpha/inv are single per-lane scalars.
// Wave = 32 q (2 groups of 16); block = 128 q; key-tiles of 64.
#define LDK 72   // 144B rows: 16B-aligned, conflict-free b128 reads
#define LDP 72
__global__ __launch_bounds__(256, 3) void attn_k(
    const unsigned short* __restrict__ qkv, unsigned short* __restrict__ outa) {
  __shared__ __align__(16) unsigned short Ks[64 * LDK];    // [key][d]
  __shared__ __align__(16) unsigned short VTs[64 * LDK];   // [d][key]
  __shared__ __align__(16) unsigned short Ps[4 * 32 * LDP];// per-wave [q][key]
  const int tid = threadIdx.x;
  const int lane = tid & 63, wave = tid >> 6;
  const int fc = lane & 15, fq = lane >> 4;
  const int bh = blockIdx.y;
  const int b = bh >> 4, h = bh & 15;
  const int qt = 15 - ((blockIdx.x + (bh >> 3)) & 15);  // swizzle for balance
  const int qw = qt * 128 + wave * 32;                  // wave's first q row

  // Q B-frags: qb[g][s] = Q[qw+g*16+fc][s*32 + fq*8 + j]
  bf16x8 qb[2][2];
#pragma unroll
  for (int g = 0; g < 2; g++) {
    const unsigned short* qrow =
        qkv + (size_t)(b * NS + qw + g * 16 + fc) * 3072 + h * 192;
    qb[g][0] = *(const bf16x8*)(qrow + fq * 8);
    qb[g][1] = *(const bf16x8*)(qrow + 32 + fq * 8);
  }

  f32x4 O[4][2];
#pragma unroll
  for (int dt = 0; dt < 4; dt++)
#pragma unroll
    for (int g = 0; g < 2; g++) O[dt][g] = (f32x4){0.f, 0.f, 0.f, 0.f};
  float msx[2] = {-3e38f, -3e38f}, lsx[2] = {0.f, 0.f};

  const int kr = tid >> 3, kc = (tid & 7) * 8;         // K staging
  const int vk = (tid & 31) * 2, vd = (tid >> 5) * 8;  // V^T staging
  unsigned short* Pw = Ps + wave * 32 * LDP;

  const int nkt = qt * 2 + 2;
  for (int kb = 0; kb < nkt; kb++) {
    const int k0 = kb * 64;
    __syncthreads();
    // stage K [64 keys x 64 d] row-major
#pragma unroll
    for (int it = 0; it < 2; it++) {
      int r = kr + it * 32;
      *(uint4*)(Ks + r * LDK + kc) = *(const uint4*)(
          qkv + (size_t)(b * NS + k0 + r) * 3072 + h * 192 + 64 + kc);
    }
    // stage V transposed: VTs[d][k]
    {
      const unsigned short* s0 =
          qkv + (size_t)(b * NS + k0 + vk) * 3072 + h * 192 + 128 + vd;
      uint4 v0 = *(const uint4*)s0;
      uint4 v1 = *(const uint4*)(s0 + 3072);
      unsigned a0[4] = {v0.x, v0.y, v0.z, v0.w};
      unsigned a1[4] = {v1.x, v1.y, v1.z, v1.w};
#pragma unroll
      for (int jj = 0; jj < 4; jj++) {
        unsigned lo = (a0[jj] & 0xffffu) | (a1[jj] << 16);
        unsigned hi = (a0[jj] >> 16) | (a1[jj] & 0xffff0000u);
        *(unsigned*)(VTs + (size_t)(vd + 2 * jj) * LDK + vk) = lo;
        *(unsigned*)(VTs + (size_t)(vd + 2 * jj + 1) * LDK + vk) = hi;
      }
    }
    __syncthreads();

    if (k0 <= qw + 31) {  // wave-uniform: skip fully-masked tiles
      // ---- S^T tiles: S[t][g], row=key=k0+t*16+fq*4+r, col=q=qw+g*16+fc
      f32x4 S[4][2];
#pragma unroll
      for (int t = 0; t < 4; t++) {
        bf16x8 ka0 = *(const bf16x8*)(Ks + (t * 16 + fc) * LDK + fq * 8);
        bf16x8 ka1 = *(const bf16x8*)(Ks + (t * 16 + fc) * LDK + 32 + fq * 8);
#pragma unroll
        for (int g = 0; g < 2; g++) {
          f32x4 s = (f32x4){0.f, 0.f, 0.f, 0.f};
          s = __builtin_amdgcn_mfma_f32_16x16x32_bf16(ka0, qb[g][0], s, 0, 0, 0);
          s = __builtin_amdgcn_mfma_f32_16x16x32_bf16(ka1, qb[g][1], s, 0, 0, 0);
          S[t][g] = s;
        }
      }
      const bool diag = (k0 + 63 > qw);
#pragma unroll
      for (int t = 0; t < 4; t++)
#pragma unroll
        for (int g = 0; g < 2; g++)
#pragma unroll
          for (int r = 0; r < 4; r++) {
            float s = S[t][g][r] * 0.125f;
            if (diag && (k0 + t * 16 + fq * 4 + r > qw + g * 16 + fc)) s = -3e38f;
            S[t][g][r] = s;
          }
      // ---- online softmax per q (in-lane 16 keys + 2 shuffles)
      float alpha[2];
#pragma unroll
      for (int g = 0; g < 2; g++) {
        float cm = S[0][g][0];
#pragma unroll
        for (int t = 0; t < 4; t++)
#pragma unroll
          for (int r = 0; r < 4; r++) cm = fmaxf(cm, S[t][g][r]);
        cm = fmaxf(cm, __shfl_xor(cm, 16, 64));
        cm = fmaxf(cm, __shfl_xor(cm, 32, 64));
        float mn = fmaxf(msx[g], cm);
        alpha[g] = __expf(msx[g] - mn);
        msx[g] = mn;
        float ps = 0.f;
#pragma unroll
        for (int t = 0; t < 4; t++)
#pragma unroll
          for (int r = 0; r < 4; r++) {
            float p = __expf(S[t][g][r] - mn);
            S[t][g][r] = p;
            ps += p;
          }
        ps += __shfl_xor(ps, 16, 64);
        ps += __shfl_xor(ps, 32, 64);
        lsx[g] = lsx[g] * alpha[g] + ps;
      }
      // ---- P store [q][key], packed b64 (r-regs contiguous)
#pragma unroll
      for (int g = 0; g < 2; g++)
#pragma unroll
        for (int t = 0; t < 4; t++) {
          ushort4 u;
          u.x = f2bf(S[t][g][0]); u.y = f2bf(S[t][g][1]);
          u.z = f2bf(S[t][g][2]); u.w = f2bf(S[t][g][3]);
          *(ushort4*)(Pw + (g * 16 + fc) * LDP + t * 16 + fq * 4) = u;
        }
      bf16x8 pb[2][2];
#pragma unroll
      for (int g = 0; g < 2; g++)
#pragma unroll
        for (int s = 0; s < 2; s++)
          pb[g][s] = *(const bf16x8*)(Pw + (g * 16 + fc) * LDP + s * 32 + fq * 8);
      // ---- rescale O by per-lane alpha, then O^T += V^T x P
#pragma unroll
      for (int dt = 0; dt < 4; dt++)
#pragma unroll
        for (int g = 0; g < 2; g++)
#pragma unroll
          for (int r = 0; r < 4; r++) O[dt][g][r] *= alpha[g];
#pragma unroll
      for (int dt = 0; dt < 4; dt++) {
        bf16x8 va0 = *(const bf16x8*)(VTs + (dt * 16 + fc) * LDK + fq * 8);
        bf16x8 va1 = *(const bf16x8*)(VTs + (dt * 16 + fc) * LDK + 32 + fq * 8);
#pragma unroll
        for (int g = 0; g < 2; g++) {
          O[dt][g] = __builtin_amdgcn_mfma_f32_16x16x32_bf16(va0, pb[g][0], O[dt][g], 0, 0, 0);
          O[dt][g] = __builtin_amdgcn_mfma_f32_16x16x32_bf16(va1, pb[g][1], O[dt][g], 0, 0, 0);
        }
      }
    }
  }

  // ---- epilogue: lane holds O^T[d=dt*16+fq*4+r][q=g*16+fc]
  float inv[2] = {1.f / lsx[0], 1.f / lsx[1]};
#pragma unroll
  for (int dt = 0; dt < 4; dt++)
#pragma unroll
    for (int g = 0; g < 2; g++) {
      ushort4 u;
      u.x = f2bf(O[dt][g][0] * inv[g]);
      u.y = f2bf(O[dt][g][1] * inv[g]);
      u.z = f2bf(O[dt][g][2] * inv[g]);
      u.w = f2bf(O[dt][g][3] * inv[g]);
      size_t row = (size_t)(b * NS) + qw + g * 16 + fc;
      *(ushort4*)(outa + row * 1024 + h * 64 + dt * 16 + fq * 4) = u;
    }
}

// ---------------- launch ----------------
// ws (bf16 elems): xb[8192*1024] | wqkv[3072*1024] | wo[1024*1024]
//                  | qkv[8192*3072] | att[8192*1024]
extern "C" void kernel_launch(void* const* d_in, const int* in_sizes, int n_in,
                              void* d_out, int out_size, void* d_ws, size_t ws_size,
                              hipStream_t stream) {
  const float* x     = (const float*)d_in[0];
  const float* qkv_w = (const float*)d_in[1];
  const float* qkv_b = (const float*)d_in[2];
  const float* out_w = (const float*)d_in[3];
  const float* out_b = (const float*)d_in[4];

  unsigned short* xb   = (unsigned short*)d_ws;
  unsigned short* wqkv = xb + (size_t)8192 * 1024;
  unsigned short* wo   = wqkv + (size_t)3072 * 1024;
  unsigned short* qkv  = wo + (size_t)1024 * 1024;
  unsigned short* att  = qkv + (size_t)8192 * 3072;

  cast_k<<<(2097152 + 255) / 256, 256, 0, stream>>>(x, xb, 2097152);
  cast_k<<<(786432 + 255) / 256, 256, 0, stream>>>(qkv_w, wqkv, 786432);
  cast_k<<<(262144 + 255) / 256, 256, 0, stream>>>(out_w, wo, 262144);

  gemm_bt<1><<<dim3(24, 64), 256, 0, stream>>>(xb, wqkv, qkv_b, (void*)qkv,
                                               8192, 3072, 1024);
  attn_k<<<dim3(16, 64), 256, 0, stream>>>(qkv, att);
  gemm_bt<0><<<dim3(8, 64), 256, 0, stream>>>(att, wo, out_b, d_out,
                                              8192, 1024, 1024);
}

// Round 5
// 289.128 us; speedup vs baseline: 7.5387x; 1.0072x over previous
//
#include <hip/hip_runtime.h>
#include <hip/hip_bf16.h>
#include <cstdint>

// Problem constants (fixed): B=4, S=2048, E=1024, H=16, HD=64
#define NB 4
#define NS 2048
#define NE 1024
#define NH 16

typedef __attribute__((ext_vector_type(8))) short bf16x8;   // 8 bf16 (4 VGPRs)
typedef __attribute__((ext_vector_type(4))) float f32x4;    // MFMA C/D

__device__ __forceinline__ unsigned short f2bf(float f) {
  unsigned u = __float_as_uint(f);
  u += 0x7fffu + ((u >> 16) & 1u);   // RNE
  return (unsigned short)(u >> 16);
}

// pack two fp32 -> bf16x2 in one b32: +0x8000 round (half-up) + v_perm
__device__ __forceinline__ unsigned pk2bf(float lo, float hi) {
  return __builtin_amdgcn_perm(__float_as_uint(hi) + 0x8000u,
                               __float_as_uint(lo) + 0x8000u, 0x07060302u);
}

__device__ __forceinline__ float exp2_fast(float x) {
#if __has_builtin(__builtin_amdgcn_exp2f)
  return __builtin_amdgcn_exp2f(x);
#else
  float r;
  asm("v_exp_f32 %0, %1" : "=v"(r) : "v"(x));
  return r;
#endif
}

// async global->LDS, 16B/lane. LDS dest = wave-uniform base + lane*16.
__device__ __forceinline__ void gl_lds16(const void* g, void* l) {
  __builtin_amdgcn_global_load_lds(
      (const __attribute__((address_space(1))) void*)g,
      (__attribute__((address_space(3))) void*)l, 16, 0, 0);
}

// ---------------- cast fp32 -> bf16 ----------------
__global__ __launch_bounds__(256) void cast_k(const float* __restrict__ in,
                                              unsigned short* __restrict__ out, int n4) {
  int idx = blockIdx.x * 256 + threadIdx.x;
  if (idx >= n4) return;
  float4 v = ((const float4*)in)[idx];
  ushort4 o;
  o.x = f2bf(v.x); o.y = f2bf(v.y); o.z = f2bf(v.z); o.w = f2bf(v.w);
  ((ushort4*)out)[idx] = o;
}

// ---------------- C = A[M,K] @ B[N,K]^T + bias ----------------
// 128x128 tile, 4 waves 2x2, 4x4 MFMA/wave, BK=64, global_load_lds staging.
// MODE 0: fp32 row-major store (out-proj). MODE 1: split per-head Q/K/VT
// scatter (Q pre-scaled by log2(e)/8 so attention scores are exp2-domain).
template <int MODE>
__global__ __launch_bounds__(256, 2) void gemm_bt(
    const unsigned short* __restrict__ A,   // [M,K] bf16
    const unsigned short* __restrict__ Bm,  // [N,K] bf16
    const float* __restrict__ bias,         // [N] fp32
    void* __restrict__ Cv,                  // MODE0: fp32 [M,N]
    unsigned short* __restrict__ Qp,        // MODE1: [bh][s][64]
    unsigned short* __restrict__ Kp,        // MODE1: [bh][s][64]
    unsigned short* __restrict__ Vp,        // MODE1: [bh][d][s]
    int M, int N, int K) {
  __shared__ __align__(16) unsigned short As[128 * 64];
  __shared__ __align__(16) unsigned short Bs[128 * 64];
  const int tid = threadIdx.x;
  const int lane = tid & 63, wave = tid >> 6;
  const int m0 = blockIdx.y * 128, n0 = blockIdx.x * 128;
  const int wm = (wave >> 1) * 64, wn = (wave & 1) * 64;
  const int fr = lane & 15, fq = lane >> 4;

  f32x4 acc[4][4];
#pragma unroll
  for (int i = 0; i < 4; i++)
#pragma unroll
    for (int j = 0; j < 4; j++) acc[i][j] = (f32x4){0.f, 0.f, 0.f, 0.f};

  const int srow = lane >> 3;                   // 0..7 within 8-row chunk
  const int scol = ((lane & 7) ^ srow) * 8;     // swizzled global col (elems)

  for (int kt = 0; kt < K; kt += 64) {
    __syncthreads();
#pragma unroll
    for (int c = 0; c < 4; c++) {
      const int chunk = wave * 4 + c;           // 0..15, 8 rows each
      const int row = chunk * 8 + srow;
      gl_lds16(A + (size_t)(m0 + row) * K + kt + scol, As + chunk * 512);
      gl_lds16(Bm + (size_t)(n0 + row) * K + kt + scol, Bs + chunk * 512);
    }
    __syncthreads();
#pragma unroll
    for (int s = 0; s < 2; s++) {
      bf16x8 af[4], bf[4];
#pragma unroll
      for (int i = 0; i < 4; i++)
        af[i] = *(const bf16x8*)(As + (wm + i * 16 + fr) * 64 +
                                 (((s * 4 + fq) ^ (fr & 7)) * 8));
#pragma unroll
      for (int j = 0; j < 4; j++)
        bf[j] = *(const bf16x8*)(Bs + (wn + j * 16 + fr) * 64 +
                                 (((s * 4 + fq) ^ (fr & 7)) * 8));
#pragma unroll
      for (int i = 0; i < 4; i++)
#pragma unroll
        for (int j = 0; j < 4; j++)
          acc[i][j] = __builtin_amdgcn_mfma_f32_16x16x32_bf16(af[i], bf[j], acc[i][j], 0, 0, 0);
    }
  }

#pragma unroll
  for (int j = 0; j < 4; j++) {
    const int col = n0 + wn + j * 16 + fr;
    const float bval = bias[col];
    const int h = col / 192, rr = col - h * 192;  // MODE1 only
#pragma unroll
    for (int i = 0; i < 4; i++)
#pragma unroll
      for (int r = 0; r < 4; r++) {
        const int row = m0 + wm + i * 16 + fq * 4 + r;
        float v = acc[i][j][r] + bval;
        if (MODE == 0) {
          ((float*)Cv)[(size_t)row * N + col] = v;
        } else {
          const int b = row >> 11, s = row & 2047;
          const int bh = b * 16 + h;
          if (rr < 64) {          // Q, pre-scaled into exp2 domain
            Qp[((size_t)bh * 2048 + s) * 64 + rr] = f2bf(v * 0.1803368802f);
          } else if (rr < 128) {  // K
            Kp[((size_t)bh * 2048 + s) * 64 + (rr - 64)] = f2bf(v);
          } else {                // V transposed [d][s]
            Vp[((size_t)bh * 64 + (rr - 128)) * 2048 + s] = f2bf(v);
          }
        }
      }
  }
}

// ---------------- MFMA causal flash attention, S^T orientation ----------------
// Q [bh][s][64] (scaled by log2e/8), K [bh][s][64], VT [bh][d][s].
// S^T = K x Q^T; online softmax per q = in-lane 16 keys + 2 shuffles.
// Each block runs q-tile pair (qt, 15-qt) -> uniform 34 key-tiles/block.
// Staging: FULL 64x64 tile per buffer = 2 uint4/thread/buffer (R4 bug was 1),
// register-prefetched across the compute phase.
#define LDK 72   // 144B rows: 16B-aligned
#define LDP 72
__global__ __launch_bounds__(256, 2) void attn_k(
    const unsigned short* __restrict__ Qg, const unsigned short* __restrict__ Kg,
    const unsigned short* __restrict__ Vg, unsigned short* __restrict__ outa) {
  __shared__ __align__(16) unsigned short Ks[64 * LDK];     // [key][d]
  __shared__ __align__(16) unsigned short VTs[64 * LDK];    // [d][key]
  __shared__ __align__(16) unsigned short Ps[4 * 32 * LDP]; // per-wave [q][key]
  const int tid = threadIdx.x;
  const int lane = tid & 63, wave = tid >> 6;
  const int fc = lane & 15, fq = lane >> 4;
  const int bh = blockIdx.y;
  const int b = bh >> 4, h = bh & 15;
  const int kr = tid >> 3, kc = (tid & 7) * 8;   // 8 lanes/row, rows kr, kr+32
  const unsigned short* Qb = Qg + (size_t)bh * 2048 * 64;
  const unsigned short* Kb = Kg + (size_t)bh * 2048 * 64;
  const unsigned short* Vb = Vg + (size_t)bh * 64 * 2048;
  unsigned short* Pw = Ps + wave * 32 * LDP;

#pragma unroll 1
  for (int phase = 0; phase < 2; phase++) {
    const int qt = phase ? 15 - (int)blockIdx.x : (int)blockIdx.x;
    const int qw = qt * 128 + wave * 32;

    // Q B-frags: qb[g][s] = Q[qw+g*16+fc][s*32 + fq*8 + j]
    bf16x8 qb[2][2];
#pragma unroll
    for (int g = 0; g < 2; g++) {
      const unsigned short* qrow = Qb + (size_t)(qw + g * 16 + fc) * 64;
      qb[g][0] = *(const bf16x8*)(qrow + fq * 8);
      qb[g][1] = *(const bf16x8*)(qrow + 32 + fq * 8);
    }

    f32x4 O[4][2];
#pragma unroll
    for (int dt = 0; dt < 4; dt++)
#pragma unroll
      for (int g = 0; g < 2; g++) O[dt][g] = (f32x4){0.f, 0.f, 0.f, 0.f};
    float msx[2] = {-3e38f, -3e38f}, lsx[2] = {0.f, 0.f};

    const int nkt = qt * 2 + 2;
    uint4 kreg[2], vreg[2];
#pragma unroll
    for (int it = 0; it < 2; it++) {
      kreg[it] = *(const uint4*)(Kb + (size_t)(kr + it * 32) * 64 + kc);
      vreg[it] = *(const uint4*)(Vb + (size_t)(kr + it * 32) * 2048 + kc);
    }

#pragma unroll 1
    for (int kb = 0; kb < nkt; kb++) {
      const int k0 = kb * 64;
      __syncthreads();
#pragma unroll
      for (int it = 0; it < 2; it++) {
        *(uint4*)(Ks + (kr + it * 32) * LDK + kc) = kreg[it];
        *(uint4*)(VTs + (kr + it * 32) * LDK + kc) = vreg[it];
      }
      __syncthreads();
      if (kb + 1 < nkt) {  // prefetch next tile (in flight across compute)
#pragma unroll
        for (int it = 0; it < 2; it++) {
          kreg[it] = *(const uint4*)(Kb + (size_t)(k0 + 64 + kr + it * 32) * 64 + kc);
          vreg[it] = *(const uint4*)(Vb + (size_t)(kr + it * 32) * 2048 + (k0 + 64) + kc);
        }
      }

      if (k0 <= qw + 31) {  // wave-uniform: skip fully-masked tiles
        // S^T tiles: row=key=k0+t*16+fq*4+r, col=q=qw+g*16+fc (exp2 domain)
        f32x4 S[4][2];
#pragma unroll
        for (int t = 0; t < 4; t++) {
          bf16x8 ka0 = *(const bf16x8*)(Ks + (t * 16 + fc) * LDK + fq * 8);
          bf16x8 ka1 = *(const bf16x8*)(Ks + (t * 16 + fc) * LDK + 32 + fq * 8);
#pragma unroll
          for (int g = 0; g < 2; g++) {
            f32x4 s = (f32x4){0.f, 0.f, 0.f, 0.f};
            s = __builtin_amdgcn_mfma_f32_16x16x32_bf16(ka0, qb[g][0], s, 0, 0, 0);
            s = __builtin_amdgcn_mfma_f32_16x16x32_bf16(ka1, qb[g][1], s, 0, 0, 0);
            S[t][g] = s;
          }
        }
        if (k0 + 63 > qw) {  // diagonal tiles only
#pragma unroll
          for (int t = 0; t < 4; t++)
#pragma unroll
            for (int g = 0; g < 2; g++)
#pragma unroll
              for (int r = 0; r < 4; r++)
                if (k0 + t * 16 + fq * 4 + r > qw + g * 16 + fc) S[t][g][r] = -3e38f;
        }
        // online softmax per q: 16 keys in-lane + xor16/xor32 shuffles
        float alpha[2];
#pragma unroll
        for (int g = 0; g < 2; g++) {
          float cm = S[0][g][0];
#pragma unroll
          for (int t = 0; t < 4; t++)
#pragma unroll
            for (int r = 0; r < 4; r++) cm = fmaxf(cm, S[t][g][r]);
          cm = fmaxf(cm, __shfl_xor(cm, 16, 64));
          cm = fmaxf(cm, __shfl_xor(cm, 32, 64));
          float mn = fmaxf(msx[g], cm);
          alpha[g] = exp2_fast(msx[g] - mn);
          msx[g] = mn;
          float ps = 0.f;
#pragma unroll
          for (int t = 0; t < 4; t++)
#pragma unroll
            for (int r = 0; r < 4; r++) {
              float p = exp2_fast(S[t][g][r] - mn);
              S[t][g][r] = p;
              ps += p;
            }
          ps += __shfl_xor(ps, 16, 64);
          ps += __shfl_xor(ps, 32, 64);
          lsx[g] = lsx[g] * alpha[g] + ps;
        }
        // P store [q][key]: perm-packed pairs, b64 per (g,t)
#pragma unroll
        for (int g = 0; g < 2; g++)
#pragma unroll
          for (int t = 0; t < 4; t++) {
            uint2 u;
            u.x = pk2bf(S[t][g][0], S[t][g][1]);
            u.y = pk2bf(S[t][g][2], S[t][g][3]);
            *(uint2*)(Pw + (g * 16 + fc) * LDP + t * 16 + fq * 4) = u;
          }
        bf16x8 pb[2][2];
#pragma unroll
        for (int g = 0; g < 2; g++)
#pragma unroll
          for (int s = 0; s < 2; s++)
            pb[g][s] = *(const bf16x8*)(Pw + (g * 16 + fc) * LDP + s * 32 + fq * 8);
        // rescale O, then O^T += V^T x P
#pragma unroll
        for (int dt = 0; dt < 4; dt++)
#pragma unroll
          for (int g = 0; g < 2; g++)
#pragma unroll
            for (int r = 0; r < 4; r++) O[dt][g][r] *= alpha[g];
#pragma unroll
        for (int dt = 0; dt < 4; dt++) {
          bf16x8 va0 = *(const bf16x8*)(VTs + (dt * 16 + fc) * LDK + fq * 8);
          bf16x8 va1 = *(const bf16x8*)(VTs + (dt * 16 + fc) * LDK + 32 + fq * 8);
#pragma unroll
          for (int g = 0; g < 2; g++) {
            O[dt][g] = __builtin_amdgcn_mfma_f32_16x16x32_bf16(va0, pb[g][0], O[dt][g], 0, 0, 0);
            O[dt][g] = __builtin_amdgcn_mfma_f32_16x16x32_bf16(va1, pb[g][1], O[dt][g], 0, 0, 0);
          }
        }
      }
    }

    // epilogue: lane holds O^T[d=dt*16+fq*4+r][q=g*16+fc]
    float inv[2] = {1.f / lsx[0], 1.f / lsx[1]};
#pragma unroll
    for (int dt = 0; dt < 4; dt++)
#pragma unroll
      for (int g = 0; g < 2; g++) {
        uint2 u;
        u.x = pk2bf(O[dt][g][0] * inv[g], O[dt][g][1] * inv[g]);
        u.y = pk2bf(O[dt][g][2] * inv[g], O[dt][g][3] * inv[g]);
        size_t row = (size_t)(b * NS) + qw + g * 16 + fc;
        *(uint2*)(outa + row * 1024 + h * 64 + dt * 16 + fq * 4) = u;
      }
  }
}

// ---------------- launch ----------------
// ws (bf16 elems): xb[8192*1024] | wqkv[3072*1024] | wo[1024*1024]
//                  | Q[64*2048*64] | K[64*2048*64] | VT[64*64*2048] | att[8192*1024]
extern "C" void kernel_launch(void* const* d_in, const int* in_sizes, int n_in,
                              void* d_out, int out_size, void* d_ws, size_t ws_size,
                              hipStream_t stream) {
  const float* x     = (const float*)d_in[0];
  const float* qkv_w = (const float*)d_in[1];
  const float* qkv_b = (const float*)d_in[2];
  const float* out_w = (const float*)d_in[3];
  const float* out_b = (const float*)d_in[4];

  unsigned short* xb   = (unsigned short*)d_ws;
  unsigned short* wqkv = xb + (size_t)8192 * 1024;
  unsigned short* wo   = wqkv + (size_t)3072 * 1024;
  unsigned short* Qg   = wo + (size_t)1024 * 1024;
  unsigned short* Kg   = Qg + (size_t)64 * 2048 * 64;
  unsigned short* Vg   = Kg + (size_t)64 * 2048 * 64;
  unsigned short* att  = Vg + (size_t)64 * 64 * 2048;

  cast_k<<<(2097152 + 255) / 256, 256, 0, stream>>>(x, xb, 2097152);
  cast_k<<<(786432 + 255) / 256, 256, 0, stream>>>(qkv_w, wqkv, 786432);
  cast_k<<<(262144 + 255) / 256, 256, 0, stream>>>(out_w, wo, 262144);

  gemm_bt<1><<<dim3(24, 64), 256, 0, stream>>>(xb, wqkv, qkv_b, nullptr,
                                               Qg, Kg, Vg, 8192, 3072, 1024);
  attn_k<<<dim3(8, 64), 256, 0, stream>>>(Qg, Kg, Vg, att);
  gemm_bt<0><<<dim3(8, 64), 256, 0, stream>>>(att, wo, out_b, d_out,
                                              nullptr, nullptr, nullptr,
                                              8192, 1024, 1024);
}